// Round 3
// baseline (1592.056 us; speedup 1.0000x reference)
//
#include <hip/hip_runtime.h>
#include <hip/hip_fp16.h>

#define DIM 64
#define RPB 128            // rows per bucket
#define RPB_SHIFT 7
#define HTILE 16384        // edges per block in hist/binpack

// ---------- fallback (round-1) atomic scatter ----------
__global__ __launch_bounds__(256) void scatter_kernel(
    const int* __restrict__ rows, const int* __restrict__ cols,
    const float* __restrict__ vals, const float* __restrict__ feat,
    float* __restrict__ x, int E)
{
    unsigned long long t = (unsigned long long)blockIdx.x * blockDim.x + threadIdx.x;
    int e = (int)(t >> 6);
    int d = (int)(t & 63);
    if (e >= E) return;
    int r = rows[e];
    int c = cols[e];
    float v = vals[e];
    float f = feat[(size_t)c * DIM + d];
    atomicAdd(&x[(size_t)r * DIM + d], v * f);
}

// ---------- feat fp32 -> fp16 table ----------
__global__ __launch_bounds__(256) void cvt_kernel(
    const float* __restrict__ f, __half* __restrict__ h, int n2)
{
    int i = blockIdx.x * blockDim.x + threadIdx.x;
    if (i < n2) {
        float2 v = ((const float2*)f)[i];
        __half2 o;
        o.x = __float2half(v.x);
        o.y = __float2half(v.y);
        ((__half2*)h)[i] = o;
    }
}

// ---------- bucket histogram (LDS-aggregated) ----------
__global__ __launch_bounds__(1024) void hist_kernel(
    const int* __restrict__ rows, int* __restrict__ gcnt, int E, int B)
{
    extern __shared__ int lcnt[];
    for (int i = threadIdx.x; i < B; i += 1024) lcnt[i] = 0;
    __syncthreads();
    int base = blockIdx.x * HTILE;
#pragma unroll
    for (int k = 0; k < HTILE / 1024; ++k) {
        int e = base + k * 1024 + threadIdx.x;
        if (e < E) atomicAdd(&lcnt[rows[e] >> RPB_SHIFT], 1);
    }
    __syncthreads();
    for (int i = threadIdx.x; i < B; i += 1024)
        if (lcnt[i]) atomicAdd(&gcnt[i], lcnt[i]);
}

// ---------- exclusive scan of <=1024 bucket counts, single block ----------
__global__ __launch_bounds__(1024) void scan_kernel(
    const int* __restrict__ gcnt, int* __restrict__ offs,
    int* __restrict__ cursors, int B, int E)
{
    __shared__ int lds[1024];
    int t = threadIdx.x;
    int v = (t < B) ? gcnt[t] : 0;
    lds[t] = v;
    __syncthreads();
    for (int off = 1; off < 1024; off <<= 1) {
        int u = (t >= off) ? lds[t - off] : 0;
        __syncthreads();
        lds[t] += u;
        __syncthreads();
    }
    int excl = lds[t] - v;
    if (t < B) { offs[t] = excl; cursors[t] = excl; }
    if (t == 0) offs[B] = E;
}

// ---------- bin edges into bucket-sorted order (block-dense writes) ----------
__global__ __launch_bounds__(1024) void binpack_kernel(
    const int* __restrict__ rows, const int* __restrict__ cols,
    const float* __restrict__ vals, int* __restrict__ cursors,
    unsigned long long* __restrict__ sorted, int E, int B)
{
    extern __shared__ int l[];
    int* cnt = l;
    int* bse = l + B;
    for (int i = threadIdx.x; i < B; i += 1024) cnt[i] = 0;
    __syncthreads();
    int tbase = blockIdx.x * HTILE;
#pragma unroll
    for (int k = 0; k < HTILE / 1024; ++k) {
        int e = tbase + k * 1024 + threadIdx.x;
        if (e < E) atomicAdd(&cnt[rows[e] >> RPB_SHIFT], 1);
    }
    __syncthreads();
    for (int i = threadIdx.x; i < B; i += 1024) {
        int c = cnt[i];
        bse[i] = c ? atomicAdd(&cursors[i], c) : 0;
    }
    __syncthreads();
    for (int i = threadIdx.x; i < B; i += 1024) cnt[i] = 0;
    __syncthreads();
#pragma unroll
    for (int k = 0; k < HTILE / 1024; ++k) {
        int e = tbase + k * 1024 + threadIdx.x;
        if (e < E) {
            int r = rows[e];
            int b = r >> RPB_SHIFT;
            int slot = bse[b] + atomicAdd(&cnt[b], 1);
            unsigned long long pk =
                ((unsigned long long)__float_as_uint(vals[e]) << 32) |
                ((unsigned long long)(r & (RPB - 1)) << 17) |
                (unsigned)cols[e];
            sorted[slot] = pk;
        }
    }
}

// ---------- per-bucket LDS accumulate: x rows for bucket b ----------
__global__ __launch_bounds__(512) void accumulate_kernel(
    const unsigned long long* __restrict__ sorted, const int* __restrict__ offs,
    const __half* __restrict__ featH, float* __restrict__ x, int N)
{
    __shared__ float ldsx[RPB * DIM];   // 32 KB
    for (int i = threadIdx.x; i < RPB * DIM; i += 512) ldsx[i] = 0.f;
    __syncthreads();

    int b = blockIdx.x;
    int s = offs[b], t = offs[b + 1];
    int lane = threadIdx.x & 63;
    int wave = threadIdx.x >> 6;        // 0..7
    const int ILP = 8;

    for (int e0 = s + wave * ILP; e0 < t; e0 += 8 * ILP) {
        int m = t - e0;
        unsigned long long pk[ILP];
        float fv[ILP];
#pragma unroll
        for (int j = 0; j < ILP; ++j)
            if (j < m) pk[j] = sorted[e0 + j];
#pragma unroll
        for (int j = 0; j < ILP; ++j)
            if (j < m) {
                int c = (int)(pk[j] & 0x1FFFF);
                fv[j] = __half2float(featH[(size_t)c * DIM + lane]);
            }
#pragma unroll
        for (int j = 0; j < ILP; ++j)
            if (j < m) {
                int rl = (int)((pk[j] >> 17) & (RPB - 1));
                float v = __uint_as_float((unsigned)(pk[j] >> 32));
                atomicAdd(&ldsx[rl * DIM + lane], v * fv[j]);
            }
    }
    __syncthreads();

    int row0 = b * RPB;
    for (int i = threadIdx.x; i < RPB * DIM / 4; i += 512) {
        int row = row0 + (i * 4) / DIM;
        if (row < N)
            ((float4*)x)[(size_t)row0 * (DIM / 4) + i] = ((const float4*)ldsx)[i];
    }
}

// ---------- out = (f+x)@W1 + (f*x)@W2 + (b1+b2) ----------
__global__ __launch_bounds__(256) void transform_kernel(
    const float* __restrict__ feat, const float* __restrict__ x,
    const float* __restrict__ W1, const float* __restrict__ b1,
    const float* __restrict__ W2, const float* __restrict__ b2,
    float* __restrict__ out, int N)
{
    const int lane = threadIdx.x & 63;

    float w1c[DIM], w2c[DIM];
#pragma unroll
    for (int k = 0; k < DIM; ++k) {
        w1c[k] = W1[k * DIM + lane];
        w2c[k] = W2[k * DIM + lane];
    }
    const float bsum = b1[lane] + b2[lane];

    const int wave   = (int)((blockIdx.x * blockDim.x + threadIdx.x) >> 6);
    const int nwaves = (int)((gridDim.x * blockDim.x) >> 6);

    for (int n = wave; n < N; n += nwaves) {
        float f  = feat[n * DIM + lane];
        float xv = x[n * DIM + lane];
        float a = f + xv;
        float b = f * xv;
        float acc = bsum;
#pragma unroll
        for (int k = 0; k < DIM; ++k) {
            float ak = __builtin_bit_cast(float,
                __builtin_amdgcn_readlane(__builtin_bit_cast(int, a), k));
            float bk = __builtin_bit_cast(float,
                __builtin_amdgcn_readlane(__builtin_bit_cast(int, b), k));
            acc = fmaf(ak, w1c[k], acc);
            acc = fmaf(bk, w2c[k], acc);
        }
        out[n * DIM + lane] = acc;
    }
}

extern "C" void kernel_launch(void* const* d_in, const int* in_sizes, int n_in,
                              void* d_out, int out_size, void* d_ws, size_t ws_size,
                              hipStream_t stream)
{
    const int*   rows = (const int*)d_in[0];
    const int*   cols = (const int*)d_in[1];
    const float* vals = (const float*)d_in[2];
    const float* feat = (const float*)d_in[3];
    const float* W1   = (const float*)d_in[4];
    const float* b1   = (const float*)d_in[5];
    const float* W2   = (const float*)d_in[6];
    const float* b2   = (const float*)d_in[7];
    float* out = (float*)d_out;

    const int E = in_sizes[0];
    const int N = in_sizes[3] / DIM;
    const int B = (N + RPB - 1) / RPB;          // buckets

    // workspace layout
    char* ws = (char*)d_ws;
    size_t xBytes     = (size_t)N * DIM * sizeof(float);            // 25.6 MB
    size_t hBytes     = (((size_t)N * DIM * sizeof(__half)) + 255) / 256 * 256; // 12.8 MB
    size_t offsBytes  = (((size_t)(B + 1) * sizeof(int)) + 255) / 256 * 256;
    size_t cursBytes  = (((size_t)B * sizeof(int)) + 255) / 256 * 256;
    size_t sortBytes  = (size_t)E * 8;                              // 25.6 MB

    float*              x       = (float*)ws;
    __half*             featH   = (__half*)(ws + xBytes);
    int*                offs    = (int*)(ws + xBytes + hBytes);
    int*                cursors = (int*)(ws + xBytes + hBytes + offsBytes);
    unsigned long long* sorted  = (unsigned long long*)(ws + xBytes + hBytes + offsBytes + cursBytes);
    size_t need = xBytes + hBytes + offsBytes + cursBytes + sortBytes;

    const int NT = (E + HTILE - 1) / HTILE;     // tiles for hist/binpack

    if (ws_size >= need && B <= 1024 && N <= 131072) {
        cvt_kernel<<<(N * DIM / 2 + 255) / 256, 256, 0, stream>>>(feat, featH, N * DIM / 2);
        hipMemsetAsync(offs, 0, (size_t)(B + 1) * sizeof(int), stream);
        hist_kernel<<<NT, 1024, (size_t)B * 4, stream>>>(rows, offs, E, B);
        // scan reads counts from offs (in gcnt position) -> write offs/cursors
        scan_kernel<<<1, 1024, 0, stream>>>(offs, offs, cursors, B, E);
        binpack_kernel<<<NT, 1024, (size_t)B * 8, stream>>>(rows, cols, vals,
                                                            cursors, sorted, E, B);
        accumulate_kernel<<<B, 512, 0, stream>>>(sorted, offs, featH, x, N);
    } else {
        hipMemsetAsync(x, 0, xBytes, stream);
        unsigned long long threads = (unsigned long long)E * DIM;
        unsigned int blocks = (unsigned int)((threads + 255ull) / 256ull);
        scatter_kernel<<<blocks, 256, 0, stream>>>(rows, cols, vals, feat, x, E);
    }

    transform_kernel<<<2048, 256, 0, stream>>>(feat, x, W1, b1, W2, b2, out, N);
}

// Round 4
// 1418.270 us; speedup vs baseline: 1.1225x; 1.1225x over previous
//
#include <hip/hip_runtime.h>
#include <hip/hip_fp16.h>

#define DIM 64
#define RPB 64             // rows per bucket
#define RPB_SHIFT 6
#define HTILE 16384        // edges per block in hist/binpack

// ---------- fallback (round-1) atomic scatter ----------
__global__ __launch_bounds__(256) void scatter_kernel(
    const int* __restrict__ rows, const int* __restrict__ cols,
    const float* __restrict__ vals, const float* __restrict__ feat,
    float* __restrict__ x, int E)
{
    unsigned long long t = (unsigned long long)blockIdx.x * blockDim.x + threadIdx.x;
    int e = (int)(t >> 6);
    int d = (int)(t & 63);
    if (e >= E) return;
    int r = rows[e];
    int c = cols[e];
    float v = vals[e];
    float f = feat[(size_t)c * DIM + d];
    atomicAdd(&x[(size_t)r * DIM + d], v * f);
}

// ---------- feat fp32 -> fp16 table ----------
__global__ __launch_bounds__(256) void cvt_kernel(
    const float* __restrict__ f, __half* __restrict__ h, int n2)
{
    int i = blockIdx.x * blockDim.x + threadIdx.x;
    if (i < n2) {
        float2 v = ((const float2*)f)[i];
        __half2 o;
        o.x = __float2half(v.x);
        o.y = __float2half(v.y);
        ((__half2*)h)[i] = o;
    }
}

// ---------- bucket histogram (LDS-aggregated) ----------
__global__ __launch_bounds__(1024) void hist_kernel(
    const int* __restrict__ rows, int* __restrict__ gcnt, int E, int B)
{
    extern __shared__ int lcnt[];
    for (int i = threadIdx.x; i < B; i += 1024) lcnt[i] = 0;
    __syncthreads();
    int base = blockIdx.x * HTILE;
#pragma unroll
    for (int k = 0; k < HTILE / 1024; ++k) {
        int e = base + k * 1024 + threadIdx.x;
        if (e < E) atomicAdd(&lcnt[rows[e] >> RPB_SHIFT], 1);
    }
    __syncthreads();
    for (int i = threadIdx.x; i < B; i += 1024)
        if (lcnt[i]) atomicAdd(&gcnt[i], lcnt[i]);
}

// ---------- exclusive scan of <=2048 bucket counts, single block ----------
__global__ __launch_bounds__(1024) void scan_kernel(
    const int* __restrict__ gcnt, int* __restrict__ offs,
    int* __restrict__ cursors, int B, int E)
{
    __shared__ int lds[2048];
    int t = threadIdx.x;
    int c0 = (t < B) ? gcnt[t] : 0;
    int c1 = (t + 1024 < B) ? gcnt[t + 1024] : 0;
    lds[t] = c0;
    lds[t + 1024] = c1;
    __syncthreads();
    for (int off = 1; off < 2048; off <<= 1) {
        int a = (t >= off) ? lds[t - off] : 0;
        int b = lds[t + 1024 - off];          // t+1024-off >= 0 always (off<=1024)
        __syncthreads();
        lds[t] += a;
        lds[t + 1024] += b;
        __syncthreads();
    }
    if (t < B)        { offs[t] = lds[t] - c0;               cursors[t] = lds[t] - c0; }
    if (t + 1024 < B) { offs[t + 1024] = lds[t + 1024] - c1; cursors[t + 1024] = lds[t + 1024] - c1; }
    if (t == 0) offs[B] = E;
}

// ---------- bin edges into bucket-sorted order (block-dense writes) ----------
__global__ __launch_bounds__(1024) void binpack_kernel(
    const int* __restrict__ rows, const int* __restrict__ cols,
    const float* __restrict__ vals, int* __restrict__ cursors,
    unsigned long long* __restrict__ sorted, int E, int B)
{
    extern __shared__ int l[];
    int* cnt = l;
    int* bse = l + B;
    for (int i = threadIdx.x; i < B; i += 1024) cnt[i] = 0;
    __syncthreads();
    int tbase = blockIdx.x * HTILE;
#pragma unroll
    for (int k = 0; k < HTILE / 1024; ++k) {
        int e = tbase + k * 1024 + threadIdx.x;
        if (e < E) atomicAdd(&cnt[rows[e] >> RPB_SHIFT], 1);
    }
    __syncthreads();
    for (int i = threadIdx.x; i < B; i += 1024) {
        int c = cnt[i];
        bse[i] = c ? atomicAdd(&cursors[i], c) : 0;
    }
    __syncthreads();
    for (int i = threadIdx.x; i < B; i += 1024) cnt[i] = 0;
    __syncthreads();
#pragma unroll
    for (int k = 0; k < HTILE / 1024; ++k) {
        int e = tbase + k * 1024 + threadIdx.x;
        if (e < E) {
            int r = rows[e];
            int b = r >> RPB_SHIFT;
            int slot = bse[b] + atomicAdd(&cnt[b], 1);
            unsigned long long pk =
                ((unsigned long long)__float_as_uint(vals[e]) << 32) |
                ((unsigned long long)(r & (RPB - 1)) << 17) |
                (unsigned)cols[e];
            sorted[slot] = pk;
        }
    }
}

// ---------- per-bucket LDS accumulate ----------
// 8 waves/block; each wave processes UNGUARDED groups of 8 edges so the
// compiler keeps 8 independent gathers in flight (the R3 version's per-j
// guards serialized everything -> VGPR_Count 20, one load in flight).
__global__ __launch_bounds__(512) void accumulate_kernel(
    const unsigned long long* __restrict__ sorted, const int* __restrict__ offs,
    const __half* __restrict__ featH, float* __restrict__ x, int N)
{
    __shared__ float ldsx[RPB * DIM];   // 16 KB -> 4 blocks/CU (thread-limited)
    for (int i = threadIdx.x; i < RPB * DIM; i += 512) ldsx[i] = 0.f;
    __syncthreads();

    int b = blockIdx.x;
    int s = offs[b], t = offs[b + 1];
    int lane = threadIdx.x & 63;
    int wave = threadIdx.x >> 6;        // 0..7

    int total = t - s;
    int ngf = total >> 3;               // full groups of 8

    for (int g = wave; g < ngf; g += 8) {
        const unsigned long long* p = sorted + s + (g << 3);
        unsigned long long pk[8];
#pragma unroll
        for (int j = 0; j < 8; ++j) pk[j] = p[j];
        float fv[8];
#pragma unroll
        for (int j = 0; j < 8; ++j) {
            unsigned c = (unsigned)(pk[j] & 0x1FFFFu);
            fv[j] = __half2float(featH[(size_t)c * DIM + lane]);
        }
#pragma unroll
        for (int j = 0; j < 8; ++j) {
            int rl = (int)((pk[j] >> 17) & (RPB - 1));
            float v = __uint_as_float((unsigned)(pk[j] >> 32));
            atomicAdd(&ldsx[rl * DIM + lane], v * fv[j]);
        }
    }
    // partial tail group (<8 edges), owned by the wave that would get group ngf
    int rem = total & 7;
    if (rem && wave == (ngf & 7)) {
        int e0 = s + (ngf << 3);
        for (int k = 0; k < rem; ++k) {
            unsigned long long pk = sorted[e0 + k];
            unsigned c = (unsigned)(pk & 0x1FFFFu);
            int rl = (int)((pk >> 17) & (RPB - 1));
            float v = __uint_as_float((unsigned)(pk >> 32));
            float f = __half2float(featH[(size_t)c * DIM + lane]);
            atomicAdd(&ldsx[rl * DIM + lane], v * f);
        }
    }
    __syncthreads();

    int row0 = b * RPB;
    for (int i = threadIdx.x; i < RPB * DIM / 4; i += 512) {
        int row = row0 + (i * 4) / DIM;
        if (row < N)
            ((float4*)x)[(size_t)row0 * (DIM / 4) + i] = ((const float4*)ldsx)[i];
    }
}

// ---------- out = (f+x)@W1 + (f*x)@W2 + (b1+b2) ----------
__global__ __launch_bounds__(256) void transform_kernel(
    const float* __restrict__ feat, const float* __restrict__ x,
    const float* __restrict__ W1, const float* __restrict__ b1,
    const float* __restrict__ W2, const float* __restrict__ b2,
    float* __restrict__ out, int N)
{
    const int lane = threadIdx.x & 63;

    float w1c[DIM], w2c[DIM];
#pragma unroll
    for (int k = 0; k < DIM; ++k) {
        w1c[k] = W1[k * DIM + lane];
        w2c[k] = W2[k * DIM + lane];
    }
    const float bsum = b1[lane] + b2[lane];

    const int wave   = (int)((blockIdx.x * blockDim.x + threadIdx.x) >> 6);
    const int nwaves = (int)((gridDim.x * blockDim.x) >> 6);

    for (int n = wave; n < N; n += nwaves) {
        float f  = feat[n * DIM + lane];
        float xv = x[n * DIM + lane];
        float a = f + xv;
        float b = f * xv;
        float acc = bsum;
#pragma unroll
        for (int k = 0; k < DIM; ++k) {
            float ak = __builtin_bit_cast(float,
                __builtin_amdgcn_readlane(__builtin_bit_cast(int, a), k));
            float bk = __builtin_bit_cast(float,
                __builtin_amdgcn_readlane(__builtin_bit_cast(int, b), k));
            acc = fmaf(ak, w1c[k], acc);
            acc = fmaf(bk, w2c[k], acc);
        }
        out[n * DIM + lane] = acc;
    }
}

extern "C" void kernel_launch(void* const* d_in, const int* in_sizes, int n_in,
                              void* d_out, int out_size, void* d_ws, size_t ws_size,
                              hipStream_t stream)
{
    const int*   rows = (const int*)d_in[0];
    const int*   cols = (const int*)d_in[1];
    const float* vals = (const float*)d_in[2];
    const float* feat = (const float*)d_in[3];
    const float* W1   = (const float*)d_in[4];
    const float* b1   = (const float*)d_in[5];
    const float* W2   = (const float*)d_in[6];
    const float* b2   = (const float*)d_in[7];
    float* out = (float*)d_out;

    const int E = in_sizes[0];
    const int N = in_sizes[3] / DIM;
    const int B = (N + RPB - 1) / RPB;          // buckets

    // workspace layout
    char* ws = (char*)d_ws;
    size_t xBytes     = (size_t)N * DIM * sizeof(float);            // 25.6 MB
    size_t hBytes     = (((size_t)N * DIM * sizeof(__half)) + 255) / 256 * 256; // 12.8 MB
    size_t offsBytes  = (((size_t)(B + 1) * sizeof(int)) + 255) / 256 * 256;
    size_t cursBytes  = (((size_t)B * sizeof(int)) + 255) / 256 * 256;
    size_t sortBytes  = (size_t)E * 8;                              // 25.6 MB

    float*              x       = (float*)ws;
    __half*             featH   = (__half*)(ws + xBytes);
    int*                offs    = (int*)(ws + xBytes + hBytes);
    int*                cursors = (int*)(ws + xBytes + hBytes + offsBytes);
    unsigned long long* sorted  = (unsigned long long*)(ws + xBytes + hBytes + offsBytes + cursBytes);
    size_t need = xBytes + hBytes + offsBytes + cursBytes + sortBytes;

    const int NT = (E + HTILE - 1) / HTILE;     // tiles for hist/binpack

    if (ws_size >= need && B <= 2048 && N <= 131072) {
        cvt_kernel<<<(N * DIM / 2 + 255) / 256, 256, 0, stream>>>(feat, featH, N * DIM / 2);
        hipMemsetAsync(offs, 0, (size_t)(B + 1) * sizeof(int), stream);
        hist_kernel<<<NT, 1024, (size_t)B * 4, stream>>>(rows, offs, E, B);
        scan_kernel<<<1, 1024, 0, stream>>>(offs, offs, cursors, B, E);
        binpack_kernel<<<NT, 1024, (size_t)B * 8, stream>>>(rows, cols, vals,
                                                            cursors, sorted, E, B);
        accumulate_kernel<<<B, 512, 0, stream>>>(sorted, offs, featH, x, N);
    } else {
        hipMemsetAsync(x, 0, xBytes, stream);
        unsigned long long threads = (unsigned long long)E * DIM;
        unsigned int blocks = (unsigned int)((threads + 255ull) / 256ull);
        scatter_kernel<<<blocks, 256, 0, stream>>>(rows, cols, vals, feat, x, E);
    }

    transform_kernel<<<2048, 256, 0, stream>>>(feat, x, W1, b1, W2, b2, out, N);
}